// Round 1
// baseline (522.899 us; speedup 1.0000x reference)
//
#include <hip/hip_runtime.h>
#include <hip/hip_bf16.h>
#include <stdint.h>

typedef __bf16 bf16x8 __attribute__((ext_vector_type(8)));
typedef float f32x4 __attribute__((ext_vector_type(4)));

#define ETILE 128
#define WT1_OFF 0
#define WT2_OFF 65536
#define WT3_OFF 98304
#define WTG1_OFF 106496
#define WTOT 122880

// LDS XOR swizzle (Guideline 4): rows at 512B/256B stride are same-bank; spread 8 rows
// across distinct 16B slots. Bijective within each row's range; preserves 16B alignment
// for col%8==0 accesses.
__device__ __forceinline__ uint32_t swz(uint32_t row, uint32_t col, uint32_t strideB) {
    return (row * strideB + col * 2u) ^ ((row & 7u) << 4);
}

__device__ __forceinline__ unsigned short f2bf_bits(float v) {
    __bf16 h = (__bf16)v;
    return __builtin_bit_cast(unsigned short, h);
}

// Transpose + downconvert all weight matrices to bf16 Wt[n][k] in workspace.
__global__ void prep_weights(const float* __restrict__ W1, const float* __restrict__ W2,
                             const float* __restrict__ W3, const float* __restrict__ Wg1,
                             unsigned short* __restrict__ ws) {
    int idx = blockIdx.x * 256 + threadIdx.x;
    if (idx >= WTOT) return;
    float v;
    if (idx < WT2_OFF) {                     // Wt1 [256n][256k] <- W1[256k][256n]
        int n = idx >> 8, k = idx & 255; v = W1[k * 256 + n];
    } else if (idx < WT3_OFF) {              // Wt2 [128n][256k] <- W2[256k][128n]
        int loc = idx - WT2_OFF; int n = loc >> 8, k = loc & 255; v = W2[k * 128 + n];
    } else if (idx < WTG1_OFF) {             // Wt3 [64n][128k] <- W3[128k][64n]
        int loc = idx - WT3_OFF; int n = loc >> 7, k = loc & 127; v = W3[k * 64 + n];
    } else {                                 // Wtg1 [64n][256k] <- Wg1[256k][64n]
        int loc = idx - WTG1_OFF; int n = loc >> 8, k = loc & 255; v = Wg1[k * 64 + n];
    }
    ws[idx] = f2bf_bits(v);
}

__global__ __launch_bounds__(512, 2)
void fused_edge_kernel(const float* __restrict__ h_user, const float* __restrict__ h_item,
                       const int* __restrict__ src, const int* __restrict__ dst,
                       const unsigned short* __restrict__ wsmat,
                       const float* __restrict__ b1, const float* __restrict__ b2,
                       const float* __restrict__ b3, const float* __restrict__ b4,
                       const float* __restrict__ W4, const float* __restrict__ bg1,
                       const float* __restrict__ Wg2, const float* __restrict__ bg2,
                       float* __restrict__ out, int E) {
    // 64KB + 64KB + 512B = 131.5KB LDS -> 1 block/CU, 8 waves (2/SIMD)
    __shared__ __align__(16) unsigned short lds_e[ETILE * 256];   // e; later x2 [128][128]
    __shared__ __align__(16) unsigned short lds_x1[ETILE * 256];  // x1
    __shared__ float lds_dot[ETILE];

    const unsigned short* wt1  = wsmat + WT1_OFF;
    const unsigned short* wt2  = wsmat + WT2_OFF;
    const unsigned short* wt3  = wsmat + WT3_OFF;
    const unsigned short* wtg1 = wsmat + WTG1_OFF;

    const int t   = threadIdx.x;
    const int eb  = blockIdx.x * ETILE;
    const int w   = t >> 6;     // wave 0..7
    const int l   = t & 63;
    const int l15 = l & 15;
    const int l4  = l >> 4;

    // ---- Phase 0: gather e = [h_user[src] | h_item[dst]] -> lds_e bf16 [128][256]
    {
        const int r = t >> 2, q = t & 3;
        int e = eb + r; if (e >= E) e = E - 1;   // clamp tail: real data, output guarded
        const int idx = (q < 2) ? src[e] : dst[e];
        const float* rowp = ((q < 2) ? h_user : h_item) + (size_t)idx * 128 + (q & 1) * 64;
        const uint32_t cbase = (uint32_t)q * 64u;
        #pragma unroll
        for (int i = 0; i < 8; ++i) {
            f32x4 a = *reinterpret_cast<const f32x4*>(rowp + i * 8);
            f32x4 b = *reinterpret_cast<const f32x4*>(rowp + i * 8 + 4);
            bf16x8 p;
            #pragma unroll
            for (int j = 0; j < 4; ++j) { p[j] = (__bf16)a[j]; p[j + 4] = (__bf16)b[j]; }
            *reinterpret_cast<bf16x8*>((char*)lds_e + swz(r, cbase + i * 8u, 512)) = p;
        }
    }
    __syncthreads();

    // ---- dot_scores = sum(s*d) in f32 from LDS bf16
    {
        const int r = t >> 2, q = t & 3;
        float acc = 0.f;
        #pragma unroll
        for (int i = 0; i < 4; ++i) {
            uint32_t c = (uint32_t)q * 32u + i * 8u;
            bf16x8 sv = *reinterpret_cast<const bf16x8*>((const char*)lds_e + swz(r, c, 512));
            bf16x8 dv = *reinterpret_cast<const bf16x8*>((const char*)lds_e + swz(r, 128u + c, 512));
            #pragma unroll
            for (int j = 0; j < 8; ++j) acc += (float)sv[j] * (float)dv[j];
        }
        acc += __shfl_xor(acc, 1);
        acc += __shfl_xor(acc, 2);
        if (q == 0) lds_dot[r] = acc;
    }

    // ---- Phase 1: x1 = relu(e @ W1 + b1) [128x256] -> lds_x1
    // wave tile 64 rows x 64 cols: mg = w>>2, cg = w&3. A-in-reg per K-half.
    {
        const int mg = w >> 2, cg = w & 3;
        f32x4 acc[4][4] = {};
        #pragma unroll
        for (int kh = 0; kh < 2; ++kh) {
            bf16x8 afr[4][4];
            #pragma unroll
            for (int mt = 0; mt < 4; ++mt)
                #pragma unroll
                for (int kt = 0; kt < 4; ++kt)
                    afr[mt][kt] = *reinterpret_cast<const bf16x8*>((const char*)lds_e +
                        swz(mg * 64 + mt * 16 + l15, kh * 128 + kt * 32 + l4 * 8, 512));
            #pragma unroll
            for (int nt = 0; nt < 4; ++nt) {
                const int n = cg * 64 + nt * 16 + l15;
                #pragma unroll
                for (int kt = 0; kt < 4; ++kt) {
                    const int k = kh * 128 + kt * 32 + l4 * 8;
                    bf16x8 bfr = *reinterpret_cast<const bf16x8*>(wt1 + n * 256 + k);
                    #pragma unroll
                    for (int mt = 0; mt < 4; ++mt)
                        acc[mt][nt] = __builtin_amdgcn_mfma_f32_16x16x32_bf16(
                            afr[mt][kt], bfr, acc[mt][nt], 0, 0, 0);
                }
            }
        }
        #pragma unroll
        for (int nt = 0; nt < 4; ++nt) {
            const int col = cg * 64 + nt * 16 + l15;
            const float bias = b1[col];
            #pragma unroll
            for (int mt = 0; mt < 4; ++mt) {
                const int row0 = mg * 64 + mt * 16 + l4 * 4;
                #pragma unroll
                for (int j = 0; j < 4; ++j) {
                    float v = fmaxf(acc[mt][nt][j] + bias, 0.f);
                    *reinterpret_cast<unsigned short*>((char*)lds_x1 + swz(row0 + j, col, 512)) = f2bf_bits(v);
                }
            }
        }
    }

    // ---- Phase 2: g = relu(e @ Wg1 + bg1), rows w*16, all 64 cols in-wave; G2 fused in-reg
    float l0p[4] = {0, 0, 0, 0}, l1p[4] = {0, 0, 0, 0};
    {
        bf16x8 ag[8];
        #pragma unroll
        for (int kt = 0; kt < 8; ++kt)
            ag[kt] = *reinterpret_cast<const bf16x8*>((const char*)lds_e +
                swz(w * 16 + l15, kt * 32 + l4 * 8, 512));
        f32x4 accg[4] = {};
        #pragma unroll
        for (int nt = 0; nt < 4; ++nt) {
            const int n = nt * 16 + l15;
            #pragma unroll
            for (int kt = 0; kt < 8; ++kt) {
                bf16x8 bfr = *reinterpret_cast<const bf16x8*>(wtg1 + n * 256 + kt * 32 + l4 * 8);
                accg[nt] = __builtin_amdgcn_mfma_f32_16x16x32_bf16(ag[kt], bfr, accg[nt], 0, 0, 0);
            }
        }
        #pragma unroll
        for (int nt = 0; nt < 4; ++nt) {
            const int col = nt * 16 + l15;
            const float bg = bg1[col];
            const float w0 = Wg2[col * 2 + 0], w1 = Wg2[col * 2 + 1];
            #pragma unroll
            for (int j = 0; j < 4; ++j) {
                float v = fmaxf(accg[nt][j] + bg, 0.f);
                l0p[j] += v * w0; l1p[j] += v * w1;
            }
        }
        #pragma unroll
        for (int j = 0; j < 4; ++j) {
            #pragma unroll
            for (int m = 1; m < 16; m <<= 1) {
                l0p[j] += __shfl_xor(l0p[j], m);
                l1p[j] += __shfl_xor(l1p[j], m);
            }
        }
    }
    __syncthreads();  // x1 writes complete AND all lds_e readers done (L2 overwrites lds_e)

    // ---- Phase 3: x2 = relu(x1 @ W2 + b2) [128x128] -> lds_e region (stride 256B)
    {
        const int mg = w >> 1, cg = w & 1;  // 32-row x 64-col wave tile
        bf16x8 a2[2][8];
        #pragma unroll
        for (int mt = 0; mt < 2; ++mt)
            #pragma unroll
            for (int kt = 0; kt < 8; ++kt)
                a2[mt][kt] = *reinterpret_cast<const bf16x8*>((const char*)lds_x1 +
                    swz(mg * 32 + mt * 16 + l15, kt * 32 + l4 * 8, 512));
        f32x4 acc2[2][4] = {};
        #pragma unroll
        for (int nt = 0; nt < 4; ++nt) {
            const int n = cg * 64 + nt * 16 + l15;
            #pragma unroll
            for (int kt = 0; kt < 8; ++kt) {
                bf16x8 bfr = *reinterpret_cast<const bf16x8*>(wt2 + n * 256 + kt * 32 + l4 * 8);
                #pragma unroll
                for (int mt = 0; mt < 2; ++mt)
                    acc2[mt][nt] = __builtin_amdgcn_mfma_f32_16x16x32_bf16(
                        a2[mt][kt], bfr, acc2[mt][nt], 0, 0, 0);
            }
        }
        #pragma unroll
        for (int nt = 0; nt < 4; ++nt) {
            const int col = cg * 64 + nt * 16 + l15;
            const float bias = b2[col];
            #pragma unroll
            for (int mt = 0; mt < 2; ++mt) {
                const int row0 = mg * 32 + mt * 16 + l4 * 4;
                #pragma unroll
                for (int j = 0; j < 4; ++j) {
                    float v = fmaxf(acc2[mt][nt][j] + bias, 0.f);
                    *reinterpret_cast<unsigned short*>((char*)lds_e + swz(row0 + j, col, 256)) = f2bf_bits(v);
                }
            }
        }
    }
    __syncthreads();

    // ---- Phase 4: x3 = relu(x2 @ W3 + b3), rows w*16, 64 cols in-wave; L4 head fused
    float mlpp[4] = {0, 0, 0, 0};
    {
        bf16x8 a3[4];
        #pragma unroll
        for (int kt = 0; kt < 4; ++kt)
            a3[kt] = *reinterpret_cast<const bf16x8*>((const char*)lds_e +
                swz(w * 16 + l15, kt * 32 + l4 * 8, 256));
        f32x4 acc3[4] = {};
        #pragma unroll
        for (int nt = 0; nt < 4; ++nt) {
            const int n = nt * 16 + l15;
            #pragma unroll
            for (int kt = 0; kt < 4; ++kt) {
                bf16x8 bfr = *reinterpret_cast<const bf16x8*>(wt3 + n * 128 + kt * 32 + l4 * 8);
                acc3[nt] = __builtin_amdgcn_mfma_f32_16x16x32_bf16(a3[kt], bfr, acc3[nt], 0, 0, 0);
            }
        }
        #pragma unroll
        for (int nt = 0; nt < 4; ++nt) {
            const int col = nt * 16 + l15;
            const float b3v = b3[col];
            const float w4v = W4[col];
            #pragma unroll
            for (int j = 0; j < 4; ++j) {
                float v = fmaxf(acc3[nt][j] + b3v, 0.f);
                mlpp[j] += v * w4v;
            }
        }
        #pragma unroll
        for (int j = 0; j < 4; ++j)
            #pragma unroll
            for (int m = 1; m < 16; m <<= 1)
                mlpp[j] += __shfl_xor(mlpp[j], m);
    }

    // ---- Phase 5: stable 2-way softmax gate + fused output
    if (l15 == 0) {
        #pragma unroll
        for (int j = 0; j < 4; ++j) {
            const int r = w * 16 + l4 * 4 + j;
            const int e = eb + r;
            if (e < E) {
                const float dot = lds_dot[r];
                const float mlp = mlpp[j] + b4[0];
                const float L0 = l0p[j] + bg2[0];
                const float L1 = l1p[j] + bg2[1];
                const float d = L1 - L0;
                const float z = __expf(-fabsf(d));
                const float inv = 1.f / (1.f + z);
                const float g1 = (d >= 0.f) ? inv : z * inv;
                out[e] = (1.f - g1) * dot + g1 * mlp;
            }
        }
    }
}

extern "C" void kernel_launch(void* const* d_in, const int* in_sizes, int n_in,
                              void* d_out, int out_size, void* d_ws, size_t ws_size,
                              hipStream_t stream) {
    const float* h_user = (const float*)d_in[0];
    const float* h_item = (const float*)d_in[1];
    const int*   src    = (const int*)d_in[2];
    const int*   dst    = (const int*)d_in[3];
    const float* W1  = (const float*)d_in[4];
    const float* b1  = (const float*)d_in[5];
    const float* W2  = (const float*)d_in[6];
    const float* b2  = (const float*)d_in[7];
    const float* W3  = (const float*)d_in[8];
    const float* b3  = (const float*)d_in[9];
    const float* W4  = (const float*)d_in[10];
    const float* b4  = (const float*)d_in[11];
    const float* Wg1 = (const float*)d_in[12];
    const float* bg1 = (const float*)d_in[13];
    const float* Wg2 = (const float*)d_in[14];
    const float* bg2 = (const float*)d_in[15];
    const int E = in_sizes[2];

    unsigned short* ws = (unsigned short*)d_ws;

    prep_weights<<<(WTOT + 255) / 256, 256, 0, stream>>>(W1, W2, W3, Wg1, ws);

    const int nblk = (E + ETILE - 1) / ETILE;
    fused_edge_kernel<<<nblk, 512, 0, stream>>>(
        h_user, h_item, src, dst, ws,
        b1, b2, b3, b4, W4, bg1, Wg2, bg2,
        (float*)d_out, E);
}